// Round 16
// baseline (67.876 us; speedup 1.0000x reference)
//
#include <hip/hip_runtime.h>
#include <math.h>

#define H   128
#define NS  1024
#define NE  512
#define M   1024
#define K2  2.8853900817779268f   // 2*log2(e): tanh(x) = 1 - 2/(1+exp2(K2*x))

__device__ __forceinline__ float exp2_fast(float x) {
#if __has_builtin(__builtin_amdgcn_exp2f)
    return __builtin_amdgcn_exp2f(x);
#else
    return __expf(x * 0.6931471805599453f);
#endif
}

__device__ __forceinline__ float fast_tanh(float x) {
    float e = __expf(2.0f * x);
    float r = __builtin_amdgcn_rcpf(1.0f + e);
    return 1.0f - 2.0f * r;
}

// ---- transpose (+K2 scale) the weight matrices ---------------------------
__global__ __launch_bounds__(256) void k_tr(const float* __restrict__ Wc_s,
                                            const float* __restrict__ Wc_e,
                                            const float* __restrict__ W_lin,
                                            float* __restrict__ WT_s1, float* __restrict__ WT_s2,
                                            float* __restrict__ WT_e1, float* __restrict__ WT_e2,
                                            float* __restrict__ WT_lin) {
    int idx = blockIdx.x * 256 + threadIdx.x;
    if (idx < 65536) {
        int t = idx >> 14, r = idx & 16383, k = r >> 7, hh = r & 127;
        const float* src = (t < 2) ? Wc_s : Wc_e;
        int off = (t & 1) * H;
        float v = K2 * src[hh * 256 + off + k];
        float* dst = (t == 0) ? WT_s1 : (t == 1) ? WT_s2 : (t == 2) ? WT_e1 : WT_e2;
        dst[r] = v;
    } else {
        int j2 = idx - 65536;             // [0, 49152)
        int k = j2 >> 7, a = j2 & 127;
        WT_lin[j2] = W_lin[a * 384 + k];
    }
}

// ---- projections -> exp2 domain ------------------------------------------
__global__ __launch_bounds__(256) void k_proj(const float* __restrict__ stmts,
                                              const float* __restrict__ eres,
                                              const float* __restrict__ attender,
                                              const float* __restrict__ WT_s1,
                                              const float* __restrict__ WT_s2,
                                              const float* __restrict__ WT_e1,
                                              const float* __restrict__ WT_e2,
                                              const float* __restrict__ bc_s,
                                              const float* __restrict__ bc_e,
                                              float* __restrict__ EAT_s, float* __restrict__ EB_s,
                                              float* __restrict__ EAT_e, float* __restrict__ EB_e) {
    __shared__ float xr[16][H];
    __shared__ float red[16][H];
    int b   = blockIdx.x;
    int tid = threadIdx.x;
    int t    = tid & 127;
    int half = tid >> 7;

    if (b < 96) {
        const float *X, *WT, *bias; float* OT; int r0, N;
        if (b < 64) { X = stmts; WT = WT_s1; bias = bc_s; OT = EAT_s; r0 = b * 16;        N = NS; }
        else        { X = eres;  WT = WT_e1; bias = bc_e; OT = EAT_e; r0 = (b - 64) * 16; N = NE; }
        for (int i = tid; i < 16 * H; i += 256) xr[i >> 7][i & 127] = X[(r0 + (i >> 7)) * H + (i & 127)];
        __syncthreads();
        float b0 = (half == 0) ? K2 * bias[t] : 0.0f;
        float acc[16];
        #pragma unroll
        for (int r = 0; r < 16; ++r) acc[r] = b0;
        int k0 = half * 64;
        #pragma unroll 4
        for (int k = k0; k < k0 + 64; ++k) {
            float wv = WT[k * H + t];
            #pragma unroll
            for (int r = 0; r < 16; ++r) acc[r] += xr[r][k] * wv;
        }
        if (half) {
            #pragma unroll
            for (int r = 0; r < 16; ++r) red[r][t] = acc[r];
        }
        __syncthreads();
        if (!half) {
            #pragma unroll
            for (int r = 0; r < 16; ++r) xr[r][t] = exp2_fast(acc[r] + red[r][t]);
        }
        __syncthreads();
        {
            int hh  = tid >> 1;
            int seg = (tid & 1) * 8;
            float4 v0 = make_float4(xr[seg + 0][hh], xr[seg + 1][hh], xr[seg + 2][hh], xr[seg + 3][hh]);
            float4 v1 = make_float4(xr[seg + 4][hh], xr[seg + 5][hh], xr[seg + 6][hh], xr[seg + 7][hh]);
            *(float4*)(OT + (size_t)hh * N + r0 + seg)     = v0;
            *(float4*)(OT + (size_t)hh * N + r0 + seg + 4) = v1;
        }
    } else {
        int b2 = b - 96;
        const float* WT = (b2 < 256) ? WT_s2 : WT_e2;
        float* O        = (b2 < 256) ? EB_s : EB_e;
        int r0          = (b2 & 255) * 4;
        float* xf = &xr[0][0];
        xf[tid]       = attender[r0 * H + tid];
        xf[tid + 256] = attender[r0 * H + 256 + tid];
        __syncthreads();
        float acc[4] = {0.f, 0.f, 0.f, 0.f};
        int k0 = half * 64;
        #pragma unroll 8
        for (int k = k0; k < k0 + 64; ++k) {
            float wv = WT[k * H + t];
            #pragma unroll
            for (int r = 0; r < 4; ++r) acc[r] += xf[r * H + k] * wv;
        }
        if (half) {
            #pragma unroll
            for (int r = 0; r < 4; ++r) red[r][t] = acc[r];
        }
        __syncthreads();
        if (!half) {
            #pragma unroll
            for (int r = 0; r < 4; ++r) O[(r0 + r) * H + t] = exp2_fast(acc[r] + red[r][t]);
        }
    }
}

// ---- fused score + softmax + context --------------------------------------
// score = -2 * sum_h ws[h]/(1+Ea*Eb)   (softmax-invariant const dropped)
// Block: 4 m's x 512 threads. s-blocks (b<256): 2 n-rows/thread; e: 1 row.
// w stays in LDS; ctx[4][H] written scaled. Register prefetch on a-chunks.
#define PAIR(eax, eay, ebx, eby, wx, wy, accv)                 \
    { float q0 = fmaf(eax, ebx, 1.0f);                         \
      float q1 = fmaf(eay, eby, 1.0f);                         \
      float nn = wx * q1; nn = fmaf(wy, q0, nn);               \
      float rr = __builtin_amdgcn_rcpf(q0 * q1);               \
      accv = fmaf(nn, rr, accv); }

__global__ __launch_bounds__(512, 4) void k_score_ctx(const float* __restrict__ EAT_s,
                                                      const float* __restrict__ EB_s,
                                                      const float* __restrict__ ws_s,
                                                      const float* __restrict__ EAT_e,
                                                      const float* __restrict__ EB_e,
                                                      const float* __restrict__ ws_e,
                                                      const float* __restrict__ stmts,
                                                      const float* __restrict__ eres,
                                                      float* __restrict__ ctx_s,
                                                      float* __restrict__ ctx_e) {
    __shared__ float Bs[4][H];          // 2 KB
    __shared__ float wbuf[1024][4];     // 16 KB (e-blocks use rows 0..511)
    __shared__ float part[4][4][H];     // 8 KB
    __shared__ float scrm[8][4], scrs[8][4], rzl[4];

    int b = blockIdx.x;                 // 0..511
    bool is_e = (b >= 256);
    int m0 = (is_e ? (b - 256) : b) * 4;
    const float* EAT = is_e ? EAT_e : EAT_s;
    const float* EB  = is_e ? EB_e  : EB_s;
    const float* wsv = is_e ? ws_e  : ws_s;
    const float* X   = is_e ? eres  : stmts;
    float* ctxout    = is_e ? ctx_e : ctx_s;
    int N    = is_e ? NE : NS;
    int ROWS = is_e ? 1 : 2;
    int t = threadIdx.x;

    Bs[t >> 7][t & 127] = EB[(size_t)(m0 + (t >> 7)) * H + (t & 127)];
    __syncthreads();

    // ---- score loop with register prefetch ----
    float acc[2][4] = {{0.f,0.f,0.f,0.f},{0.f,0.f,0.f,0.f}};
    float a[2][8];
    #pragma unroll
    for (int k = 0; k < 8; ++k) a[0][k] = EAT[(size_t)k * N + t];
    if (ROWS > 1) {
        #pragma unroll
        for (int k = 0; k < 8; ++k) a[1][k] = EAT[(size_t)k * N + t + 512];
    }
    #pragma unroll
    for (int ch = 0; ch < 16; ++ch) {
        int h0 = ch * 8;
        float an[2][8];
        if (ch < 15) {
            #pragma unroll
            for (int k = 0; k < 8; ++k) an[0][k] = EAT[(size_t)(h0 + 8 + k) * N + t];
            if (ROWS > 1) {
                #pragma unroll
                for (int k = 0; k < 8; ++k) an[1][k] = EAT[(size_t)(h0 + 8 + k) * N + t + 512];
            }
        }
        float wv[8];
        #pragma unroll
        for (int k = 0; k < 8; ++k) wv[k] = wsv[h0 + k];      // uniform -> s_load
        #pragma unroll
        for (int mj = 0; mj < 4; ++mj) {
            float bv[8];
            #pragma unroll
            for (int k = 0; k < 8; ++k) bv[k] = Bs[mj][h0 + k];   // broadcast
            PAIR(a[0][0], a[0][1], bv[0], bv[1], wv[0], wv[1], acc[0][mj]);
            PAIR(a[0][2], a[0][3], bv[2], bv[3], wv[2], wv[3], acc[0][mj]);
            PAIR(a[0][4], a[0][5], bv[4], bv[5], wv[4], wv[5], acc[0][mj]);
            PAIR(a[0][6], a[0][7], bv[6], bv[7], wv[6], wv[7], acc[0][mj]);
            if (ROWS > 1) {
                PAIR(a[1][0], a[1][1], bv[0], bv[1], wv[0], wv[1], acc[1][mj]);
                PAIR(a[1][2], a[1][3], bv[2], bv[3], wv[2], wv[3], acc[1][mj]);
                PAIR(a[1][4], a[1][5], bv[4], bv[5], wv[4], wv[5], acc[1][mj]);
                PAIR(a[1][6], a[1][7], bv[6], bv[7], wv[6], wv[7], acc[1][mj]);
            }
        }
        if (ch < 15) {
            #pragma unroll
            for (int k = 0; k < 8; ++k) a[0][k] = an[0][k];
            if (ROWS > 1) {
                #pragma unroll
                for (int k = 0; k < 8; ++k) a[1][k] = an[1][k];
            }
        }
    }

    // ---- block-wide max & sum per mj ----
    int wave = t >> 6;
    float mx[4];
    for (int mj = 0; mj < 4; ++mj) {
        float v = -2.0f * acc[0][mj];
        if (ROWS > 1) v = fmaxf(v, -2.0f * acc[1][mj]);
        mx[mj] = v;
    }
    #pragma unroll
    for (int off = 32; off > 0; off >>= 1)
        for (int mj = 0; mj < 4; ++mj) mx[mj] = fmaxf(mx[mj], __shfl_xor(mx[mj], off, 64));
    if ((t & 63) == 0) {
        for (int mj = 0; mj < 4; ++mj) scrm[wave][mj] = mx[mj];
    }
    __syncthreads();
    for (int mj = 0; mj < 4; ++mj) {
        float r = scrm[0][mj];
        for (int i = 1; i < 8; ++i) r = fmaxf(r, scrm[i][mj]);
        mx[mj] = r;
    }

    float w0[4], w1[4], sm[4];
    for (int mj = 0; mj < 4; ++mj) {
        w0[mj] = __expf(fmaf(-2.0f, acc[0][mj], -mx[mj]));
        sm[mj] = w0[mj];
        if (ROWS > 1) { w1[mj] = __expf(fmaf(-2.0f, acc[1][mj], -mx[mj])); sm[mj] += w1[mj]; }
    }
    #pragma unroll
    for (int off = 32; off > 0; off >>= 1)
        for (int mj = 0; mj < 4; ++mj) sm[mj] += __shfl_xor(sm[mj], off, 64);
    if ((t & 63) == 0) {
        for (int mj = 0; mj < 4; ++mj) scrs[wave][mj] = sm[mj];
    }

    // stash w into LDS (never to global)
    for (int mj = 0; mj < 4; ++mj) {
        wbuf[t][mj] = w0[mj];
        if (ROWS > 1) wbuf[t + 512][mj] = w1[mj];
    }
    __syncthreads();
    if (t < 4) {
        float s = scrs[0][t];
        for (int i = 1; i < 8; ++i) s += scrs[i][t];
        rzl[t] = __builtin_amdgcn_rcpf(s);
    }
    __syncthreads();

    // ---- ctx: 4 h-groups of 128, each covers N/4 rows ----
    {
        int h = t & 127;
        int g = t >> 7;                 // 0..3
        int CH = N >> 2;                // 256 (s) or 128 (e)
        const float* Xb = X + (size_t)(g * CH) * H + h;
        const float* wb = &wbuf[g * CH][0];
        float cacc[4] = {0.f, 0.f, 0.f, 0.f};
        #pragma unroll 8
        for (int nn = 0; nn < CH; ++nn) {
            float x = Xb[(size_t)nn * H];
            float4 w4 = *(const float4*)(wb + nn * 4);   // broadcast b128
            cacc[0] += w4.x * x; cacc[1] += w4.y * x;
            cacc[2] += w4.z * x; cacc[3] += w4.w * x;
        }
        #pragma unroll
        for (int mj = 0; mj < 4; ++mj) part[g][mj][h] = cacc[mj];
    }
    __syncthreads();
    {
        int mj = t >> 7, h = t & 127;
        float s = part[0][mj][h] + part[1][mj][h] + part[2][mj][h] + part[3][mj][h];
        ctxout[(size_t)(m0 + mj) * H + h] = s * rzl[mj];
    }
}

// ---- final MLP + coherence -------------------------------------------------
__global__ __launch_bounds__(512) void k_mlp(const float* __restrict__ attender,
                                             const float* __restrict__ ctx_s,
                                             const float* __restrict__ ctx_e,
                                             const float* __restrict__ WT_lin,
                                             const float* __restrict__ b_lin,
                                             const float* __restrict__ W_coh,
                                             const float* __restrict__ b_coh,
                                             float* __restrict__ out) {
    __shared__ float feats[4][3 * H];   // 6 KB
    __shared__ float red2[8];
    int m0 = blockIdx.x * 4;
    int t  = threadIdx.x;

    for (int i = t; i < 4 * 3 * H; i += 512) {
        int r = i / (3 * H), c = i % (3 * H);
        float v;
        if (c < H)            v = attender[(size_t)(m0 + r) * H + c];
        else if (c < 2 * H)   v = ctx_s[(size_t)(m0 + r) * H + (c - H)];
        else                  v = ctx_e[(size_t)(m0 + r) * H + (c - 2 * H)];
        feats[r][c] = v;
    }
    __syncthreads();

    int a  = t & 127;
    int jm = t >> 7;
    float acc = b_lin[a];
    #pragma unroll 8
    for (int k = 0; k < 3 * H; ++k)
        acc += feats[jm][k] * WT_lin[k * H + a];
    float v = fast_tanh(acc) * W_coh[a];
    #pragma unroll
    for (int off = 32; off > 0; off >>= 1) v += __shfl_down(v, off, 64);
    if ((t & 63) == 0) red2[t >> 6] = v;
    __syncthreads();
    if (t < 4) out[m0 + t] = red2[2 * t] + red2[2 * t + 1] + b_coh[0];
}

extern "C" void kernel_launch(void* const* d_in, const int* in_sizes, int n_in,
                              void* d_out, int out_size, void* d_ws, size_t ws_size,
                              hipStream_t stream) {
    const float* stmts    = (const float*)d_in[0];
    const float* eres     = (const float*)d_in[1];
    const float* attender = (const float*)d_in[2];
    const float* Wc_s     = (const float*)d_in[3];
    const float* bc_s     = (const float*)d_in[4];
    const float* ws_s     = (const float*)d_in[5];
    const float* Wc_e     = (const float*)d_in[7];
    const float* bc_e     = (const float*)d_in[8];
    const float* ws_e     = (const float*)d_in[9];
    const float* W_lin    = (const float*)d_in[11];
    const float* b_lin    = (const float*)d_in[12];
    const float* W_coh    = (const float*)d_in[13];
    const float* b_coh    = (const float*)d_in[14];
    float* out = (float*)d_out;

    float* ws    = (float*)d_ws;
    float* WT_s1 = ws;
    float* WT_s2 = WT_s1 + H * H;
    float* WT_e1 = WT_s2 + H * H;
    float* WT_e2 = WT_e1 + H * H;
    float* WT_li = WT_e2 + H * H;             // 384*128
    float* EAT_s = WT_li + 3 * H * H;         // [H][NS]
    float* EB_s  = EAT_s + NS * H;
    float* EAT_e = EB_s + M * H;              // [H][NE]
    float* EB_e  = EAT_e + NE * H;
    float* c_s   = EB_e + M * H;              // ctx_s [M][H]
    float* c_e   = c_s + (size_t)M * H;       // ctx_e [M][H]

    k_tr<<<448, 256, 0, stream>>>(Wc_s, Wc_e, W_lin, WT_s1, WT_s2, WT_e1, WT_e2, WT_li);
    k_proj<<<608, 256, 0, stream>>>(stmts, eres, attender, WT_s1, WT_s2, WT_e1, WT_e2,
                                    bc_s, bc_e, EAT_s, EB_s, EAT_e, EB_e);
    k_score_ctx<<<512, 512, 0, stream>>>(EAT_s, EB_s, ws_s, EAT_e, EB_e, ws_e,
                                         stmts, eres, c_s, c_e);
    k_mlp<<<M / 4, 512, 0, stream>>>(attender, c_s, c_e, WT_li, b_lin, W_coh, b_coh, out);
}